// Round 1
// baseline (41.288 us; speedup 1.0000x reference)
//
#include <hip/hip_runtime.h>

#define Bz 32
#define Lz 1024
#define Hz 768
#define Sz 16

// ---------------- kernel 1: per-batch setup ----------------
// valid[b] = sum(attention_mask[b]); hist[b] = bos[b][0];
// seg[b][p] = searchsorted(bos[b], p, 'right') - 1
__global__ __launch_bounds__(256) void setup_kernel(
    const int* __restrict__ amask, const int* __restrict__ bos,
    int* __restrict__ seg, int* __restrict__ validArr, int* __restrict__ histArr) {
  int b = blockIdx.x;
  int tid = threadIdx.x;
  __shared__ int sbos[Sz];
  __shared__ int red[256];
  if (tid < Sz) sbos[tid] = bos[b * Sz + tid];
  int partial = 0;
  for (int p = tid; p < Lz; p += 256) partial += amask[b * Lz + p];
  red[tid] = partial;
  __syncthreads();
  for (int off = 128; off > 0; off >>= 1) {
    if (tid < off) red[tid] += red[tid + off];
    __syncthreads();
  }
  if (tid == 0) { validArr[b] = red[0]; histArr[b] = sbos[0]; }
  for (int p = tid; p < Lz; p += 256) {
    int sg = -1;
#pragma unroll
    for (int s = 0; s < Sz; ++s) sg += (p >= sbos[s]) ? 1 : 0;
    seg[b * Lz + p] = sg;
  }
}

// ---------------- kernel 2: per-position dot(tokens[b,p,:], fc_w) ----------------
// one wave per position; only positions in [hist, valid) are needed.
__global__ __launch_bounds__(256) void dot_kernel(
    const float* __restrict__ tokens, const float* __restrict__ fc_w,
    const int* __restrict__ validArr, const int* __restrict__ histArr,
    float* __restrict__ t) {
  // grid = Bz * (Lz/4); 4 waves per block, 1 position each
  int blocksPerBatch = Lz / 4;  // 256
  int b = blockIdx.x / blocksPerBatch;
  int local = blockIdx.x % blocksPerBatch;
  int wave = threadIdx.x >> 6;
  int lane = threadIdx.x & 63;
  int p = local * 4 + wave;
  int v = validArr[b];
  int h = histArr[b];
  if (p < h || p >= v) return;  // token row not needed at all
  const float4* tp = (const float4*)(tokens + ((size_t)b * Lz + p) * Hz);
  const float4* wp = (const float4*)fc_w;
  float sum = 0.f;
#pragma unroll
  for (int c = 0; c < 3; ++c) {  // 192 float4 = 64 lanes * 3
    float4 a = tp[lane + c * 64];
    float4 w = wp[lane + c * 64];
    sum += a.x * w.x + a.y * w.y + a.z * w.z + a.w * w.w;
  }
#pragma unroll
  for (int off = 32; off > 0; off >>= 1) sum += __shfl_down(sum, off);
  if (lane == 0) t[b * Lz + p] = sum;
}

// ---------------- kernel 3: segment means -> logits ----------------
__global__ __launch_bounds__(64) void logits_kernel(
    const float* __restrict__ t, const int* __restrict__ bos,
    const int* __restrict__ validArr, const float* __restrict__ fc_b,
    float* __restrict__ logits) {
  int b = blockIdx.x >> 4;   // grid = Bz*Sz
  int s = blockIdx.x & (Sz - 1);
  int lane = threadIdx.x;
  int beg = bos[b * Sz + s];
  int end = (s < Sz - 1) ? bos[b * Sz + s + 1] : validArr[b];
  float sum = 0.f;
  for (int p = beg + lane; p < end; p += 64) sum += t[b * Lz + p];
#pragma unroll
  for (int off = 32; off > 0; off >>= 1) sum += __shfl_down(sum, off);
  if (lane == 0) logits[b * Sz + s] = sum / (float)(end - beg) + fc_b[0];
}

// ---------------- kernel 4: mask rows ----------------
// one block per (b, q) row; 256 threads * float4 = 1024 floats
__global__ __launch_bounds__(256) void mask_kernel(
    const int* __restrict__ seg, const int* __restrict__ validArr,
    const int* __restrict__ histArr, float* __restrict__ maskOut) {
  int b = blockIdx.x >> 10;  // grid = Bz*Lz
  int q = blockIdx.x & (Lz - 1);
  int tid = threadIdx.x;
  float4* row = (float4*)(maskOut + ((size_t)(b * Lz + q)) * Lz);
  int v = validArr[b];
  if (q >= v) {
    row[tid] = make_float4(0.f, 0.f, 0.f, 0.f);
    return;
  }
  int h = histArr[b];
  int segq = seg[b * Lz + q];
  bool qh = (q < h);
  const int4* segRow = (const int4*)(seg + b * Lz);
  int4 s4 = segRow[tid];
  int p0 = tid * 4;
  float4 val;
  val.x = (p0 + 0 < v && (qh || p0 + 0 < h || s4.x == segq)) ? 1.f : 0.f;
  val.y = (p0 + 1 < v && (qh || p0 + 1 < h || s4.y == segq)) ? 1.f : 0.f;
  val.z = (p0 + 2 < v && (qh || p0 + 2 < h || s4.z == segq)) ? 1.f : 0.f;
  val.w = (p0 + 3 < v && (qh || p0 + 3 < h || s4.w == segq)) ? 1.f : 0.f;
  row[tid] = val;
}

extern "C" void kernel_launch(void* const* d_in, const int* in_sizes, int n_in,
                              void* d_out, int out_size, void* d_ws, size_t ws_size,
                              hipStream_t stream) {
  const float* tokens = (const float*)d_in[0];
  const int* amask = (const int*)d_in[1];
  const int* bos = (const int*)d_in[2];
  const float* fc_w = (const float*)d_in[3];
  const float* fc_b = (const float*)d_in[4];

  float* out = (float*)d_out;
  float* logits = out;               // Bz*Sz floats
  float* maskOut = out + Bz * Sz;    // Bz*Lz*Lz floats (0/1)

  char* ws = (char*)d_ws;
  int* seg = (int*)ws;                                 // Bz*Lz ints
  int* validArr = (int*)(ws + (size_t)Bz * Lz * 4);    // Bz ints
  int* histArr = validArr + Bz;                        // Bz ints
  float* t = (float*)(ws + (size_t)Bz * Lz * 4 + 2 * Bz * 4);  // Bz*Lz floats

  setup_kernel<<<Bz, 256, 0, stream>>>(amask, bos, seg, validArr, histArr);
  dot_kernel<<<Bz * (Lz / 4), 256, 0, stream>>>(tokens, fc_w, validArr, histArr, t);
  logits_kernel<<<Bz * Sz, 64, 0, stream>>>(t, bos, validArr, fc_b, logits);
  mask_kernel<<<Bz * Lz, 256, 0, stream>>>(seg, validArr, histArr, maskOut);
}